// Round 9
// baseline (299.110 us; speedup 1.0000x reference)
//
#include <hip/hip_runtime.h>
#include <cstdint>
#include <cstddef>

#define NB 32
#define NG 30
#define NA 8400
#define NC 80
#define SELB 512        // k_sel block size
#define MGRIDX 33       // ceil(NA/256)
#define NBLK (MGRIDX * NB)

typedef unsigned long long u64;

struct Params {
  const float* f8; const float* f16; const float* f32; const float* lab;
  float*    bbox;    // [NB*NA] float4 decoded cx,cy,w,h
  float*    objlog;  // [NB*NA] raw obj logit
  float*    po;      // [NB*NA] sigm(objlog)
  float*    base_;   // [NB*NA] -sum_c log(1-sqrt(pc*po)+eps)
  unsigned* gbits;   // [NB*NA] bits 0..29 = in_both(g); bit 31 = anchor_ok
  unsigned* mmask;   // [NB*NA] bit g set => anchor popped for gt g (pre-dedup)
  float*    acc;     // [4] loss_iou, loss_obj, loss_cls, num_fg
  unsigned* cnt;     // [1] k_match completion counter
  float*    out;     // [1] final loss
};

__device__ __forceinline__ float fsigm(float x) {
  return __fdividef(1.0f, 1.0f + __expf(-x));
}

__device__ __forceinline__ void anchor_geom(int a, int& x, int& y, int& W, int& hw,
                                            float& stride, int& lvl) {
  if (a < 6400)      { W = 80; hw = 6400; stride = 8.f;  lvl = 0; int i = a;        y = i / 80; x = i - y * 80; }
  else if (a < 8000) { W = 40; hw = 1600; stride = 16.f; lvl = 1; int i = a - 6400; y = i / 40; x = i - y * 40; }
  else               { W = 20; hw = 400;  stride = 32.f; lvl = 2; int i = a - 8000; y = i / 20; x = i - y * 20; }
}

__device__ __forceinline__ float pair_iou(float px, float py, float pw, float ph,
                                          float glx, float gty, float grx, float gby,
                                          float area_g) {
  float tlx = fmaxf(glx, px - pw * 0.5f);
  float tly = fmaxf(gty, py - ph * 0.5f);
  float brx = fminf(grx, px + pw * 0.5f);
  float bry = fminf(gby, py + ph * 0.5f);
  float inter = ((tlx < brx) && (tly < bry)) ? (brx - tlx) * (bry - tly) : 0.0f;
  return __fdividef(inter, area_g + pw * ph - inter + 1e-16f);
}

// THE cost expression — single definition, inlined into k_sel and k_match.
__device__ __forceinline__ float cost_of(float4 pb, float po, float bs, unsigned gb,
                                         int g, float glx, float gty, float grx,
                                         float gby, float area_g, float xl,
                                         float& iou_out) {
  bool ok = (gb >> 31) & 1u;
  float iou = pair_iou(pb.x, pb.y, pb.z, pb.w, glx, gty, grx, gby, area_g);
  iou = ok ? iou : 0.0f;
  float iou_cost = -__logf(iou + 1e-8f);
  float pc = fsigm(xl);
  float pr = sqrtf(pc * po);
  float cls_cost = bs - (__logf(pr + 1e-8f) - __logf(1.0f - pr + 1e-8f));
  float c = cls_cost + 3.0f * iou_cost;
  c = c + (((gb >> g) & 1u) ? 0.0f : 100000.0f);
  c = c + (ok ? 0.0f : 1000000000.0f);
  iou_out = iou;
  return c;
}

// monotone float -> sortable u32, packed with anchor idx: u64 order == lex order
__device__ __forceinline__ u64 packkey(float c, int a) {
  unsigned b = __float_as_uint(c);
  b = (b & 0x80000000u) ? ~b : (b | 0x80000000u);
  return ((u64)b << 32) | (unsigned)a;
}

// K1: per (b,a): decode, po, base, gate bits. Also zeroes mmask/acc/cnt.
__global__ __launch_bounds__(256) void k_stage(Params p) {
  __shared__ float sgt[NG * 5];
  int b = blockIdx.y;
  int tid = threadIdx.x;
  if (tid < NG * 5) sgt[tid] = p.lab[b * NG * 5 + tid];
  if (blockIdx.x == 0 && b == 0) {
    if (tid < 4) p.acc[tid] = 0.0f;
    if (tid == 4) *p.cnt = 0u;
  }
  __syncthreads();
  int a = blockIdx.x * 256 + tid;
  if (a >= NA) return;
  p.mmask[b * NA + a] = 0u;

  int x, y, W, hw, lvl; float stride;
  anchor_geom(a, x, y, W, hw, stride, lvl);
  const float* f = (lvl == 0) ? p.f8 : (lvl == 1) ? p.f16 : p.f32;
  int loff = (lvl == 0) ? 0 : (lvl == 1) ? 6400 : 8000;
  int fb = b * 85 * hw + (a - loff);    // y*W + x == level-local index

  float tx = f[fb];
  float ty = f[fb + hw];
  float tw = f[fb + 2 * hw];
  float th = f[fb + 3 * hw];
  float ob = f[fb + 4 * hw];

  float px = (tx + (float)x) * stride;
  float py = (ty + (float)y) * stride;
  float pw = __expf(tw) * stride;
  float ph = __expf(th) * stride;
  ((float4*)p.bbox)[b * NA + a] = make_float4(px, py, pw, ph);
  p.objlog[b * NA + a] = ob;

  float po = fsigm(ob);
  p.po[b * NA + a] = po;
  float bs = 0.0f;
  int cb = fb + 5 * hw;
#pragma unroll 8
  for (int c = 0; c < NC; c++) {
    float xl = f[cb + c * hw];
    float pc = fsigm(xl);
    float pr = sqrtf(pc * po);
    bs -= __logf(1.0f - pr + 1e-8f);
  }
  p.base_[b * NA + a] = bs;

  float xc = ((float)x + 0.5f) * stride;
  float yc = ((float)y + 0.5f) * stride;
  float r = 2.5f * stride;
  unsigned gb = 0; int ok = 0;
#pragma unroll
  for (int g = 0; g < NG; g++) {
    float gx = sgt[g * 5], gy = sgt[g * 5 + 1], gw = sgt[g * 5 + 2], gh = sgt[g * 5 + 3];
    bool inb = (xc > gx - 0.5f * gw) && (xc < gx + 0.5f * gw) &&
               (yc > gy - 0.5f * gh) && (yc < gy + 0.5f * gh);
    bool inc = (xc > gx - r) && (xc < gx + r) && (yc > gy - r) && (yc < gy + r);
    ok |= (inb || inc) ? 1 : 0;
    gb |= (unsigned)(inb && inc) << g;
  }
  gb |= (unsigned)ok << 31;
  p.gbits[b * NA + a] = gb;
}

// block-wide argmax of (v, carry i); result on ALL threads. (SELB threads)
__device__ __forceinline__ void block_argmax(float& v, int& i, int tid,
                                             float* swv, int* swi) {
#pragma unroll
  for (int off = 32; off; off >>= 1) {
    float v2 = __shfl_down(v, off, 64);
    int   i2 = __shfl_down(i, off, 64);
    if (v2 > v) { v = v2; i = i2; }
  }
  int wv = tid >> 6;
  if ((tid & 63) == 0) { swv[wv] = v; swi[wv] = i; }
  __syncthreads();
  float bv = swv[0]; int bi = swi[0];
#pragma unroll
  for (int w = 1; w < SELB / 64; w++) {
    if (swv[w] > bv) { bv = swv[w]; bi = swi[w]; }
  }
  v = bv; i = bi;
  __syncthreads();
}

// block-wide min of u64 key; result on ALL threads.
__device__ __forceinline__ u64 block_min_u64(u64 k, int tid, u64* swk) {
#pragma unroll
  for (int off = 32; off; off >>= 1) {
    u64 k2 = __shfl_down(k, off, 64);
    if (k2 < k) k = k2;
  }
  int wv = tid >> 6;
  if ((tid & 63) == 0) swk[wv] = k;
  __syncthreads();
  u64 m = swk[0];
#pragma unroll
  for (int w = 1; w < SELB / 64; w++) if (swk[w] < m) m = swk[w];
  __syncthreads();
  return m;
}

// K2: one block per (b,g). Per-level sub-loops (no anchor_geom — the class
// gather address is just cbase + level-local idx). Register top-10s with
// pre-filtered branch-free insertion; lex order via sortable u64 keys.
__global__ __launch_bounds__(SELB) void k_sel(Params p) {
  __shared__ float swv[SELB / 64];
  __shared__ int   swi[SELB / 64];
  __shared__ u64   swk[SELB / 64];
  int bg = blockIdx.x;
  int b = bg / NG, g = bg % NG;
  int tid = threadIdx.x;

  const float* gt = p.lab + (b * NG + g) * 5;
  float gx = gt[0], gy = gt[1], gw = gt[2], gh = gt[3];
  int cg = (int)gt[4];
  float glx = gx - 0.5f * gw, grx = gx + 0.5f * gw;
  float gty = gy - 0.5f * gh, gby = gy + 0.5f * gh;
  float area_g = gw * gh;

  const float4*   bb = (const float4*)p.bbox + b * NA;
  const float*    pov = p.po + b * NA;
  const float*    bsv = p.base_ + b * NA;
  const unsigned* gbv = p.gbits + b * NA;

  float v[10];   // top-10 ious, descending (zeros = reference zero-padding)
  u64   kv[10];  // bottom-10 lex (cost, idx) as sortable keys, ascending
#pragma unroll
  for (int j = 0; j < 10; j++) { v[j] = 0.0f; kv[j] = ~0ull; }

  auto scan_one = [&](int a, float xl) {
    unsigned gb = gbv[a];
    if (gb >> 31) {                     // anchor_ok only (exact: see R8 note)
      float4 pb = bb[a];
      float iou;
      float c = cost_of(pb, pov[a], bsv[a], gb, g,
                        glx, gty, grx, gby, area_g, xl, iou);
      if (iou > v[9]) {
        float nv = iou;
#pragma unroll
        for (int j = 0; j < 10; j++) {
          float hi = fmaxf(v[j], nv);
          nv = fminf(v[j], nv);
          v[j] = hi;
        }
      }
      u64 nk = packkey(c, a);
      if (nk < kv[9]) {
#pragma unroll
        for (int j = 0; j < 10; j++) {
          u64 lo = (kv[j] < nk) ? kv[j] : nk;
          u64 hi = (kv[j] < nk) ? nk : kv[j];
          kv[j] = lo; nk = hi;
        }
      }
    }
  };

  {
    const float* f = p.f8;
    int cbase = b * 85 * 6400 + (5 + cg) * 6400;
    for (int al = tid; al < 6400; al += SELB) scan_one(al, f[cbase + al]);
  }
  {
    const float* f = p.f16;
    int cbase = b * 85 * 1600 + (5 + cg) * 1600;
    for (int al = tid; al < 1600; al += SELB) scan_one(6400 + al, f[cbase + al]);
  }
  {
    const float* f = p.f32;
    int cbase = b * 85 * 400 + (5 + cg) * 400;
    for (int al = tid; al < 400; al += SELB) scan_one(8000 + al, f[cbase + al]);
  }

  // dyn_k = max(floor(sum top-10 ious), 1)
  float sum = 0.0f; int ptr = 0;
  for (int it = 0; it < 10; it++) {
    float mv = (ptr < 10) ? v[ptr] : -1e30f;
    int   mi = tid;
    block_argmax(mv, mi, tid, swv, swi);
    if (tid == mi) ptr++;
    sum += mv;
  }
  int dynk = (int)sum;
  if (dynk < 1) dynk = 1;

  // pop dyn_k smallest keys; each popped real key = matched anchor
  ptr = 0;
  unsigned* mrow = p.mmask + b * NA;
  unsigned gbit = 1u << g;
  for (int it = 0; it < dynk; it++) {
    u64 mk = (ptr < 10) ? kv[ptr] : ~0ull;
    u64 win = block_min_u64(mk, tid, swk);
    if (ptr < 10 && kv[ptr] == win) {   // idx embedded => unique owner
      if (win != ~0ull) atomicOr(&mrow[(unsigned)(win & 0xFFFFFFFFu)], gbit);
      ptr++;
    }
  }
}

__device__ __forceinline__ float block_sum(float val, volatile float* sw) {
#pragma unroll
  for (int off = 32; off > 0; off >>= 1) val += __shfl_down(val, off, 64);
  int lane = threadIdx.x & 63, wv = threadIdx.x >> 6;
  __syncthreads();
  if (lane == 0) sw[wv] = val;
  __syncthreads();
  float r = 0.0f;
  if (threadIdx.x == 0) r = sw[0] + sw[1] + sw[2] + sw[3];
  return r;
}

// K3: per (b,a) dedup (wave-coop cost recompute for am>1) + losses + finalize
__global__ __launch_bounds__(256) void k_match(Params p) {
  __shared__ float sred[4];
  int b = blockIdx.y;
  int tid = threadIdx.x;
  int lane = tid & 63;
  int a = blockIdx.x * 256 + tid;
  bool valid = a < NA;

  float l_iou = 0.0f, l_obj = 0.0f, l_cls = 0.0f, l_nfg = 0.0f;
  unsigned mask = 0; int am = 0;
  bool fg = false; float pred_iou = 0.0f; int cg_ = 0;

  if (valid) {
    mask = p.mmask[b * NA + a];
    am = __popc(mask);
    fg = (mask != 0u);
    float ol = p.objlog[b * NA + a];
    float tfg = fg ? 1.0f : 0.0f;
    l_obj = fmaxf(ol, 0.0f) - ol * tfg + __logf(1.0f + __expf(-fabsf(ol)));
  }

  // wave-coop dedup: lanes 0..29 recompute the cost column, lex argmin (cost,g)
  unsigned long long amb = __ballot(valid && am > 1);
  while (amb) {
    int src = __ffsll(amb) - 1;
    amb &= amb - 1ull;
    int aa = __shfl(a, src, 64);
    float4 pb = ((const float4*)p.bbox)[b * NA + aa];
    float po_ = p.po[b * NA + aa];
    float bs_ = p.base_[b * NA + aa];
    unsigned gb_ = p.gbits[b * NA + aa];

    int lvl = (aa < 6400) ? 0 : (aa < 8000) ? 1 : 2;
    int hw  = (lvl == 0) ? 6400 : (lvl == 1) ? 1600 : 400;
    int loff = (lvl == 0) ? 0 : (lvl == 1) ? 6400 : 8000;
    const float* f = (lvl == 0) ? p.f8 : (lvl == 1) ? p.f16 : p.f32;
    int cb = b * 85 * hw + 5 * hw + (aa - loff);

    float c = 3.4e38f; int gg = 0x7FFFFFFF;
    if (lane < NG) {
      const float* gtg = p.lab + (b * NG + lane) * 5;
      float gx = gtg[0], gy = gtg[1], gw = gtg[2], gh = gtg[3];
      int cg = (int)gtg[4];
      float xl = f[cb + cg * hw];
      float iou_;
      c = cost_of(pb, po_, bs_, gb_, lane,
                  gx - 0.5f * gw, gy - 0.5f * gh,
                  gx + 0.5f * gw, gy + 0.5f * gh, gw * gh, xl, iou_);
      gg = lane;
    }
#pragma unroll
    for (int off = 32; off; off >>= 1) {
      float c2 = __shfl_down(c, off, 64);
      int   g2 = __shfl_down(gg, off, 64);
      if (c2 < c || (c2 == c && g2 < gg)) { c = c2; gg = g2; }
    }
    gg = __shfl(gg, 0, 64);
    if (lane == src) mask = 1u << gg;
  }

  if (valid && fg) {
    l_nfg = 1.0f;
    int mg = __ffs(mask) - 1;
    const float* gtm = p.lab + (b * NG + mg) * 5;
    float gx = gtm[0], gy = gtm[1], gw = gtm[2], gh = gtm[3];
    cg_ = (int)gtm[4];
    float4 pb = ((const float4*)p.bbox)[b * NA + a];
    float iou = pair_iou(pb.x, pb.y, pb.z, pb.w,
                         gx - 0.5f * gw, gy - 0.5f * gh,
                         gx + 0.5f * gw, gy + 0.5f * gh, gw * gh);
    pred_iou = iou;
    l_iou = 1.0f - iou * iou;
  }

  // wave-cooperative cls-loss for fg anchors
  unsigned long long fgb = __ballot(valid && fg);
  while (fgb) {
    int src = __ffsll(fgb) - 1;
    fgb &= fgb - 1ull;
    int   aa   = __shfl(a, src, 64);
    float piou = __shfl(pred_iou, src, 64);
    int   ccg  = __shfl(cg_, src, 64);

    int lvl = (aa < 6400) ? 0 : (aa < 8000) ? 1 : 2;
    int hw  = (lvl == 0) ? 6400 : (lvl == 1) ? 1600 : 400;
    int loff = (lvl == 0) ? 0 : (lvl == 1) ? 6400 : 8000;
    const float* f = (lvl == 0) ? p.f8 : (lvl == 1) ? p.f16 : p.f32;
    int cb = b * 85 * hw + 5 * hw + (aa - loff);

    float part = 0.0f;
#pragma unroll
    for (int c0 = 0; c0 < NC; c0 += 64) {
      int c = c0 + lane;
      if (c < NC) {
        float xl = f[cb + c * hw];
        float t = (c == ccg) ? piou : 0.0f;
        part += fmaxf(xl, 0.0f) - xl * t + __logf(1.0f + __expf(-fabsf(xl)));
      }
    }
#pragma unroll
    for (int off = 32; off; off >>= 1) part += __shfl_down(part, off, 64);
    if (lane == 0) l_cls += part;
  }

  float s0 = block_sum(l_iou, sred);
  float s1 = block_sum(l_obj, sred);
  float s2 = block_sum(l_cls, sred);
  float s3 = block_sum(l_nfg, sred);
  if (tid == 0) {
    atomicAdd(&p.acc[0], s0);
    atomicAdd(&p.acc[1], s1);
    atomicAdd(&p.acc[2], s2);
    atomicAdd(&p.acc[3], s3);
    __threadfence();
    unsigned done = atomicAdd(p.cnt, 1u);
    if (done == NBLK - 1) {
      __threadfence();
      float li = atomicAdd(&p.acc[0], 0.0f);
      float lo = atomicAdd(&p.acc[1], 0.0f);
      float lc = atomicAdd(&p.acc[2], 0.0f);
      float nf = atomicAdd(&p.acc[3], 0.0f);
      p.out[0] = (5.0f * li + 0.1f * lo + lc) / fmaxf(nf, 1.0f);
    }
  }
}

extern "C" void kernel_launch(void* const* d_in, const int* in_sizes, int n_in,
                              void* d_out, int out_size, void* d_ws, size_t ws_size,
                              hipStream_t stream) {
  Params p;
  p.f8  = (const float*)d_in[0];
  p.f16 = (const float*)d_in[1];
  p.f32 = (const float*)d_in[2];
  p.lab = (const float*)d_in[3];

  float* w = (float*)d_ws;
  p.bbox   = w;              w += (size_t)NB * NA * 4;
  p.objlog = w;              w += (size_t)NB * NA;
  p.po     = w;              w += (size_t)NB * NA;
  p.base_  = w;              w += (size_t)NB * NA;
  p.gbits  = (unsigned*)w;   w += (size_t)NB * NA;
  p.mmask  = (unsigned*)w;   w += (size_t)NB * NA;
  p.acc    = w;              w += 4;
  p.cnt    = (unsigned*)w;   w += 1;
  p.out    = (float*)d_out;

  dim3 gd(MGRIDX, NB);
  k_stage<<<gd, 256, 0, stream>>>(p);
  k_sel<<<NB * NG, SELB, 0, stream>>>(p);
  k_match<<<gd, 256, 0, stream>>>(p);
}

// Round 10
// 277.519 us; speedup vs baseline: 1.0778x; 1.0778x over previous
//
#include <hip/hip_runtime.h>
#include <cstdint>
#include <cstddef>

#define NB 32
#define NG 30
#define NA 8400
#define NC 80
#define SELB 512        // k_sel block size
#define MGRIDX 33       // ceil(NA/256)
#define NBLK (MGRIDX * NB)

typedef unsigned long long u64;

struct Params {
  const float* f8; const float* f16; const float* f32; const float* lab;
  float*    bbox;    // [NB*NA] float4 decoded cx,cy,w,h
  float*    objlog;  // [NB*NA] raw obj logit
  float*    po;      // [NB*NA] sigm(objlog)
  float*    base_;   // [NB*NA] -sum_c log(1-sqrt(pc*po)+eps)
  unsigned* gbits;   // [NB*NA] bits 0..29 = in_both(g); bit 31 = anchor_ok
  unsigned* mmask;   // [NB*NA] bit g set => anchor popped for gt g (pre-dedup)
  float*    acc;     // [4] loss_iou, loss_obj, loss_cls, num_fg
  unsigned* cnt;     // [1] k_match completion counter
  float*    out;     // [1] final loss
};

__device__ __forceinline__ float fsigm(float x) {
  return __fdividef(1.0f, 1.0f + __expf(-x));
}

__device__ __forceinline__ void anchor_geom(int a, int& x, int& y, int& W, int& hw,
                                            float& stride, int& lvl) {
  if (a < 6400)      { W = 80; hw = 6400; stride = 8.f;  lvl = 0; int i = a;        y = i / 80; x = i - y * 80; }
  else if (a < 8000) { W = 40; hw = 1600; stride = 16.f; lvl = 1; int i = a - 6400; y = i / 40; x = i - y * 40; }
  else               { W = 20; hw = 400;  stride = 32.f; lvl = 2; int i = a - 8000; y = i / 20; x = i - y * 20; }
}

__device__ __forceinline__ float pair_iou(float px, float py, float pw, float ph,
                                          float glx, float gty, float grx, float gby,
                                          float area_g) {
  float tlx = fmaxf(glx, px - pw * 0.5f);
  float tly = fmaxf(gty, py - ph * 0.5f);
  float brx = fminf(grx, px + pw * 0.5f);
  float bry = fminf(gby, py + ph * 0.5f);
  float inter = ((tlx < brx) && (tly < bry)) ? (brx - tlx) * (bry - tly) : 0.0f;
  return __fdividef(inter, area_g + pw * ph - inter + 1e-16f);
}

// THE cost expression — single definition, inlined into k_sel and k_match.
__device__ __forceinline__ float cost_of(float4 pb, float po, float bs, unsigned gb,
                                         int g, float glx, float gty, float grx,
                                         float gby, float area_g, float xl,
                                         float& iou_out) {
  bool ok = (gb >> 31) & 1u;
  float iou = pair_iou(pb.x, pb.y, pb.z, pb.w, glx, gty, grx, gby, area_g);
  iou = ok ? iou : 0.0f;
  float iou_cost = -__logf(iou + 1e-8f);
  float pc = fsigm(xl);
  float pr = sqrtf(pc * po);
  float cls_cost = bs - (__logf(pr + 1e-8f) - __logf(1.0f - pr + 1e-8f));
  float c = cls_cost + 3.0f * iou_cost;
  c = c + (((gb >> g) & 1u) ? 0.0f : 100000.0f);
  c = c + (ok ? 0.0f : 1000000000.0f);
  iou_out = iou;
  return c;
}

// monotone float -> sortable u32, packed with anchor idx: u64 order == lex order
__device__ __forceinline__ u64 packkey(float c, int a) {
  unsigned b = __float_as_uint(c);
  b = (b & 0x80000000u) ? ~b : (b | 0x80000000u);
  return ((u64)b << 32) | (unsigned)a;
}

// K1: per (b,a): decode, po, base, gate bits. Also zeroes mmask/acc/cnt.
__global__ __launch_bounds__(256) void k_stage(Params p) {
  __shared__ float sgt[NG * 5];
  int b = blockIdx.y;
  int tid = threadIdx.x;
  if (tid < NG * 5) sgt[tid] = p.lab[b * NG * 5 + tid];
  if (blockIdx.x == 0 && b == 0) {
    if (tid < 4) p.acc[tid] = 0.0f;
    if (tid == 4) *p.cnt = 0u;
  }
  __syncthreads();
  int a = blockIdx.x * 256 + tid;
  if (a >= NA) return;
  p.mmask[b * NA + a] = 0u;

  int x, y, W, hw, lvl; float stride;
  anchor_geom(a, x, y, W, hw, stride, lvl);
  const float* f = (lvl == 0) ? p.f8 : (lvl == 1) ? p.f16 : p.f32;
  int loff = (lvl == 0) ? 0 : (lvl == 1) ? 6400 : 8000;
  int fb = b * 85 * hw + (a - loff);    // y*W + x == level-local index

  float tx = f[fb];
  float ty = f[fb + hw];
  float tw = f[fb + 2 * hw];
  float th = f[fb + 3 * hw];
  float ob = f[fb + 4 * hw];

  float px = (tx + (float)x) * stride;
  float py = (ty + (float)y) * stride;
  float pw = __expf(tw) * stride;
  float ph = __expf(th) * stride;
  ((float4*)p.bbox)[b * NA + a] = make_float4(px, py, pw, ph);
  p.objlog[b * NA + a] = ob;

  float po = fsigm(ob);
  p.po[b * NA + a] = po;
  float bs = 0.0f;
  int cb = fb + 5 * hw;
#pragma unroll 8
  for (int c = 0; c < NC; c++) {
    float xl = f[cb + c * hw];
    float pc = fsigm(xl);
    float pr = sqrtf(pc * po);
    bs -= __logf(1.0f - pr + 1e-8f);
  }
  p.base_[b * NA + a] = bs;

  float xc = ((float)x + 0.5f) * stride;
  float yc = ((float)y + 0.5f) * stride;
  float r = 2.5f * stride;
  unsigned gb = 0; int ok = 0;
#pragma unroll
  for (int g = 0; g < NG; g++) {
    float gx = sgt[g * 5], gy = sgt[g * 5 + 1], gw = sgt[g * 5 + 2], gh = sgt[g * 5 + 3];
    bool inb = (xc > gx - 0.5f * gw) && (xc < gx + 0.5f * gw) &&
               (yc > gy - 0.5f * gh) && (yc < gy + 0.5f * gh);
    bool inc = (xc > gx - r) && (xc < gx + r) && (yc > gy - r) && (yc < gy + r);
    ok |= (inb || inc) ? 1 : 0;
    gb |= (unsigned)(inb && inc) << g;
  }
  gb |= (unsigned)ok << 31;
  p.gbits[b * NA + a] = gb;
}

// block-wide argmax of (v, carry i); result on ALL threads. (SELB threads)
__device__ __forceinline__ void block_argmax(float& v, int& i, int tid,
                                             float* swv, int* swi) {
#pragma unroll
  for (int off = 32; off; off >>= 1) {
    float v2 = __shfl_down(v, off, 64);
    int   i2 = __shfl_down(i, off, 64);
    if (v2 > v) { v = v2; i = i2; }
  }
  int wv = tid >> 6;
  if ((tid & 63) == 0) { swv[wv] = v; swi[wv] = i; }
  __syncthreads();
  float bv = swv[0]; int bi = swi[0];
#pragma unroll
  for (int w = 1; w < SELB / 64; w++) {
    if (swv[w] > bv) { bv = swv[w]; bi = swi[w]; }
  }
  v = bv; i = bi;
  __syncthreads();
}

// block-wide min of u64 key; result on ALL threads.
__device__ __forceinline__ u64 block_min_u64(u64 k, int tid, u64* swk) {
#pragma unroll
  for (int off = 32; off; off >>= 1) {
    u64 k2 = __shfl_down(k, off, 64);
    if (k2 < k) k = k2;
  }
  int wv = tid >> 6;
  if ((tid & 63) == 0) swk[wv] = k;
  __syncthreads();
  u64 m = swk[0];
#pragma unroll
  for (int w = 1; w < SELB / 64; w++) if (swk[w] < m) m = swk[w];
  __syncthreads();
  return m;
}

// Scan body as a MACRO (no lambda!) so v[]/kv[] never have their address
// escape — keeps them fully register-resident (R9's lambda demoted v[] to
// LDS: 20 KB/block + 123k bank conflicts).
#define SCAN_ONE(A, XL)                                                   \
  {                                                                       \
    unsigned gb = gbv[(A)];                                               \
    if (gb >> 31) {                                                       \
      float4 pb = bb[(A)];                                                \
      float iou;                                                          \
      float c = cost_of(pb, pov[(A)], bsv[(A)], gb, g,                    \
                        glx, gty, grx, gby, area_g, (XL), iou);           \
      if (iou > v[9]) {                                                   \
        float nv = iou;                                                   \
        _Pragma("unroll")                                                 \
        for (int j = 0; j < 10; j++) {                                    \
          float hi = fmaxf(v[j], nv);                                     \
          nv = fminf(v[j], nv);                                           \
          v[j] = hi;                                                      \
        }                                                                 \
      }                                                                   \
      u64 nk = packkey(c, (A));                                           \
      if (nk < kv[9]) {                                                   \
        _Pragma("unroll")                                                 \
        for (int j = 0; j < 10; j++) {                                    \
          u64 lo = (kv[j] < nk) ? kv[j] : nk;                             \
          u64 hi = (kv[j] < nk) ? nk : kv[j];                             \
          kv[j] = lo; nk = hi;                                            \
        }                                                                 \
      }                                                                   \
    }                                                                     \
  }

// K2: one block per (b,g). Per-level sub-loops; register-resident top-10s.
__global__ __launch_bounds__(SELB) void k_sel(Params p) {
  __shared__ float swv[SELB / 64];
  __shared__ int   swi[SELB / 64];
  __shared__ u64   swk[SELB / 64];
  int bg = blockIdx.x;
  int b = bg / NG, g = bg % NG;
  int tid = threadIdx.x;

  const float* gt = p.lab + (b * NG + g) * 5;
  float gx = gt[0], gy = gt[1], gw = gt[2], gh = gt[3];
  int cg = (int)gt[4];
  float glx = gx - 0.5f * gw, grx = gx + 0.5f * gw;
  float gty = gy - 0.5f * gh, gby = gy + 0.5f * gh;
  float area_g = gw * gh;

  const float4*   bb = (const float4*)p.bbox + b * NA;
  const float*    pov = p.po + b * NA;
  const float*    bsv = p.base_ + b * NA;
  const unsigned* gbv = p.gbits + b * NA;

  float v[10];   // top-10 ious, descending (zeros = reference zero-padding)
  u64   kv[10];  // bottom-10 lex (cost, idx) as sortable keys, ascending
#pragma unroll
  for (int j = 0; j < 10; j++) { v[j] = 0.0f; kv[j] = ~0ull; }

  {
    const float* f = p.f8;
    int cbase = b * 85 * 6400 + (5 + cg) * 6400;
    for (int al = tid; al < 6400; al += SELB) SCAN_ONE(al, f[cbase + al]);
  }
  {
    const float* f = p.f16;
    int cbase = b * 85 * 1600 + (5 + cg) * 1600;
    for (int al = tid; al < 1600; al += SELB) SCAN_ONE(6400 + al, f[cbase + al]);
  }
  {
    const float* f = p.f32;
    int cbase = b * 85 * 400 + (5 + cg) * 400;
    for (int al = tid; al < 400; al += SELB) SCAN_ONE(8000 + al, f[cbase + al]);
  }

  // dyn_k = max(floor(sum top-10 ious), 1)
  float sum = 0.0f; int ptr = 0;
  for (int it = 0; it < 10; it++) {
    float mv = (ptr < 10) ? v[ptr] : -1e30f;
    int   mi = tid;
    block_argmax(mv, mi, tid, swv, swi);
    if (tid == mi) ptr++;
    sum += mv;
  }
  int dynk = (int)sum;
  if (dynk < 1) dynk = 1;

  // pop dyn_k smallest keys; each popped real key = matched anchor
  ptr = 0;
  unsigned* mrow = p.mmask + b * NA;
  unsigned gbit = 1u << g;
  for (int it = 0; it < dynk; it++) {
    u64 mk = (ptr < 10) ? kv[ptr] : ~0ull;
    u64 win = block_min_u64(mk, tid, swk);
    if (ptr < 10 && kv[ptr] == win) {   // idx embedded => unique owner
      if (win != ~0ull) atomicOr(&mrow[(unsigned)(win & 0xFFFFFFFFu)], gbit);
      ptr++;
    }
  }
}

__device__ __forceinline__ float block_sum(float val, volatile float* sw) {
#pragma unroll
  for (int off = 32; off > 0; off >>= 1) val += __shfl_down(val, off, 64);
  int lane = threadIdx.x & 63, wv = threadIdx.x >> 6;
  __syncthreads();
  if (lane == 0) sw[wv] = val;
  __syncthreads();
  float r = 0.0f;
  if (threadIdx.x == 0) r = sw[0] + sw[1] + sw[2] + sw[3];
  return r;
}

// K3: per (b,a) dedup (wave-coop cost recompute for am>1) + losses + finalize
__global__ __launch_bounds__(256) void k_match(Params p) {
  __shared__ float sred[4];
  int b = blockIdx.y;
  int tid = threadIdx.x;
  int lane = tid & 63;
  int a = blockIdx.x * 256 + tid;
  bool valid = a < NA;

  float l_iou = 0.0f, l_obj = 0.0f, l_cls = 0.0f, l_nfg = 0.0f;
  unsigned mask = 0; int am = 0;
  bool fg = false; float pred_iou = 0.0f; int cg_ = 0;

  if (valid) {
    mask = p.mmask[b * NA + a];
    am = __popc(mask);
    fg = (mask != 0u);
    float ol = p.objlog[b * NA + a];
    float tfg = fg ? 1.0f : 0.0f;
    l_obj = fmaxf(ol, 0.0f) - ol * tfg + __logf(1.0f + __expf(-fabsf(ol)));
  }

  // wave-coop dedup: lanes 0..29 recompute the cost column, lex argmin (cost,g)
  unsigned long long amb = __ballot(valid && am > 1);
  while (amb) {
    int src = __ffsll(amb) - 1;
    amb &= amb - 1ull;
    int aa = __shfl(a, src, 64);
    float4 pb = ((const float4*)p.bbox)[b * NA + aa];
    float po_ = p.po[b * NA + aa];
    float bs_ = p.base_[b * NA + aa];
    unsigned gb_ = p.gbits[b * NA + aa];

    int lvl = (aa < 6400) ? 0 : (aa < 8000) ? 1 : 2;
    int hw  = (lvl == 0) ? 6400 : (lvl == 1) ? 1600 : 400;
    int loff = (lvl == 0) ? 0 : (lvl == 1) ? 6400 : 8000;
    const float* f = (lvl == 0) ? p.f8 : (lvl == 1) ? p.f16 : p.f32;
    int cb = b * 85 * hw + 5 * hw + (aa - loff);

    float c = 3.4e38f; int gg = 0x7FFFFFFF;
    if (lane < NG) {
      const float* gtg = p.lab + (b * NG + lane) * 5;
      float gx = gtg[0], gy = gtg[1], gw = gtg[2], gh = gtg[3];
      int cg = (int)gtg[4];
      float xl = f[cb + cg * hw];
      float iou_;
      c = cost_of(pb, po_, bs_, gb_, lane,
                  gx - 0.5f * gw, gy - 0.5f * gh,
                  gx + 0.5f * gw, gy + 0.5f * gh, gw * gh, xl, iou_);
      gg = lane;
    }
#pragma unroll
    for (int off = 32; off; off >>= 1) {
      float c2 = __shfl_down(c, off, 64);
      int   g2 = __shfl_down(gg, off, 64);
      if (c2 < c || (c2 == c && g2 < gg)) { c = c2; gg = g2; }
    }
    gg = __shfl(gg, 0, 64);
    if (lane == src) mask = 1u << gg;
  }

  if (valid && fg) {
    l_nfg = 1.0f;
    int mg = __ffs(mask) - 1;
    const float* gtm = p.lab + (b * NG + mg) * 5;
    float gx = gtm[0], gy = gtm[1], gw = gtm[2], gh = gtm[3];
    cg_ = (int)gtm[4];
    float4 pb = ((const float4*)p.bbox)[b * NA + a];
    float iou = pair_iou(pb.x, pb.y, pb.z, pb.w,
                         gx - 0.5f * gw, gy - 0.5f * gh,
                         gx + 0.5f * gw, gy + 0.5f * gh, gw * gh);
    pred_iou = iou;
    l_iou = 1.0f - iou * iou;
  }

  // wave-cooperative cls-loss for fg anchors
  unsigned long long fgb = __ballot(valid && fg);
  while (fgb) {
    int src = __ffsll(fgb) - 1;
    fgb &= fgb - 1ull;
    int   aa   = __shfl(a, src, 64);
    float piou = __shfl(pred_iou, src, 64);
    int   ccg  = __shfl(cg_, src, 64);

    int lvl = (aa < 6400) ? 0 : (aa < 8000) ? 1 : 2;
    int hw  = (lvl == 0) ? 6400 : (lvl == 1) ? 1600 : 400;
    int loff = (lvl == 0) ? 0 : (lvl == 1) ? 6400 : 8000;
    const float* f = (lvl == 0) ? p.f8 : (lvl == 1) ? p.f16 : p.f32;
    int cb = b * 85 * hw + 5 * hw + (aa - loff);

    float part = 0.0f;
#pragma unroll
    for (int c0 = 0; c0 < NC; c0 += 64) {
      int c = c0 + lane;
      if (c < NC) {
        float xl = f[cb + c * hw];
        float t = (c == ccg) ? piou : 0.0f;
        part += fmaxf(xl, 0.0f) - xl * t + __logf(1.0f + __expf(-fabsf(xl)));
      }
    }
#pragma unroll
    for (int off = 32; off; off >>= 1) part += __shfl_down(part, off, 64);
    if (lane == 0) l_cls += part;
  }

  float s0 = block_sum(l_iou, sred);
  float s1 = block_sum(l_obj, sred);
  float s2 = block_sum(l_cls, sred);
  float s3 = block_sum(l_nfg, sred);
  if (tid == 0) {
    atomicAdd(&p.acc[0], s0);
    atomicAdd(&p.acc[1], s1);
    atomicAdd(&p.acc[2], s2);
    atomicAdd(&p.acc[3], s3);
    __threadfence();
    unsigned done = atomicAdd(p.cnt, 1u);
    if (done == NBLK - 1) {
      __threadfence();
      float li = atomicAdd(&p.acc[0], 0.0f);
      float lo = atomicAdd(&p.acc[1], 0.0f);
      float lc = atomicAdd(&p.acc[2], 0.0f);
      float nf = atomicAdd(&p.acc[3], 0.0f);
      p.out[0] = (5.0f * li + 0.1f * lo + lc) / fmaxf(nf, 1.0f);
    }
  }
}

extern "C" void kernel_launch(void* const* d_in, const int* in_sizes, int n_in,
                              void* d_out, int out_size, void* d_ws, size_t ws_size,
                              hipStream_t stream) {
  Params p;
  p.f8  = (const float*)d_in[0];
  p.f16 = (const float*)d_in[1];
  p.f32 = (const float*)d_in[2];
  p.lab = (const float*)d_in[3];

  float* w = (float*)d_ws;
  p.bbox   = w;              w += (size_t)NB * NA * 4;
  p.objlog = w;              w += (size_t)NB * NA;
  p.po     = w;              w += (size_t)NB * NA;
  p.base_  = w;              w += (size_t)NB * NA;
  p.gbits  = (unsigned*)w;   w += (size_t)NB * NA;
  p.mmask  = (unsigned*)w;   w += (size_t)NB * NA;
  p.acc    = w;              w += 4;
  p.cnt    = (unsigned*)w;   w += 1;
  p.out    = (float*)d_out;

  dim3 gd(MGRIDX, NB);
  k_stage<<<gd, 256, 0, stream>>>(p);
  k_sel<<<NB * NG, SELB, 0, stream>>>(p);
  k_match<<<gd, 256, 0, stream>>>(p);
}

// Round 11
// 217.885 us; speedup vs baseline: 1.3728x; 1.2737x over previous
//
#include <hip/hip_runtime.h>
#include <cstdint>
#include <cstddef>

#define NB 32
#define NG 30
#define NA 8400
#define NC 80
#define SELB 512        // k_sel block size
#define MGRIDX 33       // ceil(NA/256)
#define NBLK (MGRIDX * NB)

typedef unsigned long long u64;

struct Params {
  const float* f8; const float* f16; const float* f32; const float* lab;
  float*    bbox;    // [NB*NA] float4 decoded cx,cy,w,h
  float*    objlog;  // [NB*NA] raw obj logit
  float*    po;      // [NB*NA] sigm(objlog)
  float*    base_;   // [NB*NA] -sum_c log(1-sqrt(pc*po)+eps)
  unsigned* gbits;   // [NB*NA] bits 0..29 = in_both(g); bit 31 = anchor_ok
  unsigned* mmask;   // [NB*NA] bit g set => anchor popped for gt g (pre-dedup)
  float*    part;    // [NBLK] float4 per-block partial (iou, obj, cls, nfg)
  float*    out;     // [1] final loss
};

__device__ __forceinline__ float fsigm(float x) {
  return __fdividef(1.0f, 1.0f + __expf(-x));
}

__device__ __forceinline__ void anchor_geom(int a, int& x, int& y, int& W, int& hw,
                                            float& stride, int& lvl) {
  if (a < 6400)      { W = 80; hw = 6400; stride = 8.f;  lvl = 0; int i = a;        y = i / 80; x = i - y * 80; }
  else if (a < 8000) { W = 40; hw = 1600; stride = 16.f; lvl = 1; int i = a - 6400; y = i / 40; x = i - y * 40; }
  else               { W = 20; hw = 400;  stride = 32.f; lvl = 2; int i = a - 8000; y = i / 20; x = i - y * 20; }
}

__device__ __forceinline__ float pair_iou(float px, float py, float pw, float ph,
                                          float glx, float gty, float grx, float gby,
                                          float area_g) {
  float tlx = fmaxf(glx, px - pw * 0.5f);
  float tly = fmaxf(gty, py - ph * 0.5f);
  float brx = fminf(grx, px + pw * 0.5f);
  float bry = fminf(gby, py + ph * 0.5f);
  float inter = ((tlx < brx) && (tly < bry)) ? (brx - tlx) * (bry - tly) : 0.0f;
  return __fdividef(inter, area_g + pw * ph - inter + 1e-16f);
}

// THE cost expression — single definition, inlined into k_sel and k_match.
__device__ __forceinline__ float cost_of(float4 pb, float po, float bs, unsigned gb,
                                         int g, float glx, float gty, float grx,
                                         float gby, float area_g, float xl,
                                         float& iou_out) {
  bool ok = (gb >> 31) & 1u;
  float iou = pair_iou(pb.x, pb.y, pb.z, pb.w, glx, gty, grx, gby, area_g);
  iou = ok ? iou : 0.0f;
  float iou_cost = -__logf(iou + 1e-8f);
  float pc = fsigm(xl);
  float pr = sqrtf(pc * po);
  float cls_cost = bs - (__logf(pr + 1e-8f) - __logf(1.0f - pr + 1e-8f));
  float c = cls_cost + 3.0f * iou_cost;
  c = c + (((gb >> g) & 1u) ? 0.0f : 100000.0f);
  c = c + (ok ? 0.0f : 1000000000.0f);
  iou_out = iou;
  return c;
}

// monotone float -> sortable u32, packed with anchor idx: u64 order == lex order
__device__ __forceinline__ u64 packkey(float c, int a) {
  unsigned b = __float_as_uint(c);
  b = (b & 0x80000000u) ? ~b : (b | 0x80000000u);
  return ((u64)b << 32) | (unsigned)a;
}

// K1: per (b,a): decode, po, base, gate bits. Also zeroes mmask.
__global__ __launch_bounds__(256) void k_stage(Params p) {
  __shared__ float sgt[NG * 5];
  int b = blockIdx.y;
  int tid = threadIdx.x;
  if (tid < NG * 5) sgt[tid] = p.lab[b * NG * 5 + tid];
  __syncthreads();
  int a = blockIdx.x * 256 + tid;
  if (a >= NA) return;
  p.mmask[b * NA + a] = 0u;

  int x, y, W, hw, lvl; float stride;
  anchor_geom(a, x, y, W, hw, stride, lvl);
  const float* f = (lvl == 0) ? p.f8 : (lvl == 1) ? p.f16 : p.f32;
  int loff = (lvl == 0) ? 0 : (lvl == 1) ? 6400 : 8000;
  int fb = b * 85 * hw + (a - loff);    // y*W + x == level-local index

  float tx = f[fb];
  float ty = f[fb + hw];
  float tw = f[fb + 2 * hw];
  float th = f[fb + 3 * hw];
  float ob = f[fb + 4 * hw];

  float px = (tx + (float)x) * stride;
  float py = (ty + (float)y) * stride;
  float pw = __expf(tw) * stride;
  float ph = __expf(th) * stride;
  ((float4*)p.bbox)[b * NA + a] = make_float4(px, py, pw, ph);
  p.objlog[b * NA + a] = ob;

  float po = fsigm(ob);
  p.po[b * NA + a] = po;
  float bs = 0.0f;
  int cb = fb + 5 * hw;
#pragma unroll 8
  for (int c = 0; c < NC; c++) {
    float xl = f[cb + c * hw];
    float pc = fsigm(xl);
    float pr = sqrtf(pc * po);
    bs -= __logf(1.0f - pr + 1e-8f);
  }
  p.base_[b * NA + a] = bs;

  float xc = ((float)x + 0.5f) * stride;
  float yc = ((float)y + 0.5f) * stride;
  float r = 2.5f * stride;
  unsigned gb = 0; int ok = 0;
#pragma unroll
  for (int g = 0; g < NG; g++) {
    float gx = sgt[g * 5], gy = sgt[g * 5 + 1], gw = sgt[g * 5 + 2], gh = sgt[g * 5 + 3];
    bool inb = (xc > gx - 0.5f * gw) && (xc < gx + 0.5f * gw) &&
               (yc > gy - 0.5f * gh) && (yc < gy + 0.5f * gh);
    bool inc = (xc > gx - r) && (xc < gx + r) && (yc > gy - r) && (yc < gy + r);
    ok |= (inb || inc) ? 1 : 0;
    gb |= (unsigned)(inb && inc) << g;
  }
  gb |= (unsigned)ok << 31;
  p.gbits[b * NA + a] = gb;
}

// block-wide argmax of (v, carry i); result on ALL threads. (SELB threads)
__device__ __forceinline__ void block_argmax(float& v, int& i, int tid,
                                             float* swv, int* swi) {
#pragma unroll
  for (int off = 32; off; off >>= 1) {
    float v2 = __shfl_down(v, off, 64);
    int   i2 = __shfl_down(i, off, 64);
    if (v2 > v) { v = v2; i = i2; }
  }
  int wv = tid >> 6;
  if ((tid & 63) == 0) { swv[wv] = v; swi[wv] = i; }
  __syncthreads();
  float bv = swv[0]; int bi = swi[0];
#pragma unroll
  for (int w = 1; w < SELB / 64; w++) {
    if (swv[w] > bv) { bv = swv[w]; bi = swi[w]; }
  }
  v = bv; i = bi;
  __syncthreads();
}

// block-wide min of u64 key; result on ALL threads.
__device__ __forceinline__ u64 block_min_u64(u64 k, int tid, u64* swk) {
#pragma unroll
  for (int off = 32; off; off >>= 1) {
    u64 k2 = __shfl_down(k, off, 64);
    if (k2 < k) k = k2;
  }
  int wv = tid >> 6;
  if ((tid & 63) == 0) swk[wv] = k;
  __syncthreads();
  u64 m = swk[0];
#pragma unroll
  for (int w = 1; w < SELB / 64; w++) if (swk[w] < m) m = swk[w];
  __syncthreads();
  return m;
}

// Scan body as a MACRO (no lambda!) so v[]/kv[] never have their address
// escape — keeps them fully register-resident (R9's lambda demoted v[] to
// LDS: 20 KB/block + 123k bank conflicts).
#define SCAN_ONE(A, XL)                                                   \
  {                                                                       \
    unsigned gb = gbv[(A)];                                               \
    if (gb >> 31) {                                                       \
      float4 pb = bb[(A)];                                                \
      float iou;                                                          \
      float c = cost_of(pb, pov[(A)], bsv[(A)], gb, g,                    \
                        glx, gty, grx, gby, area_g, (XL), iou);           \
      if (iou > v[9]) {                                                   \
        float nv = iou;                                                   \
        _Pragma("unroll")                                                 \
        for (int j = 0; j < 10; j++) {                                    \
          float hi = fmaxf(v[j], nv);                                     \
          nv = fminf(v[j], nv);                                           \
          v[j] = hi;                                                      \
        }                                                                 \
      }                                                                   \
      u64 nk = packkey(c, (A));                                           \
      if (nk < kv[9]) {                                                   \
        _Pragma("unroll")                                                 \
        for (int j = 0; j < 10; j++) {                                    \
          u64 lo = (kv[j] < nk) ? kv[j] : nk;                             \
          u64 hi = (kv[j] < nk) ? nk : kv[j];                             \
          kv[j] = lo; nk = hi;                                            \
        }                                                                 \
      }                                                                   \
    }                                                                     \
  }

// K2: one block per (b,g). Per-level sub-loops; register-resident top-10s.
__global__ __launch_bounds__(SELB) void k_sel(Params p) {
  __shared__ float swv[SELB / 64];
  __shared__ int   swi[SELB / 64];
  __shared__ u64   swk[SELB / 64];
  int bg = blockIdx.x;
  int b = bg / NG, g = bg % NG;
  int tid = threadIdx.x;

  const float* gt = p.lab + (b * NG + g) * 5;
  float gx = gt[0], gy = gt[1], gw = gt[2], gh = gt[3];
  int cg = (int)gt[4];
  float glx = gx - 0.5f * gw, grx = gx + 0.5f * gw;
  float gty = gy - 0.5f * gh, gby = gy + 0.5f * gh;
  float area_g = gw * gh;

  const float4*   bb = (const float4*)p.bbox + b * NA;
  const float*    pov = p.po + b * NA;
  const float*    bsv = p.base_ + b * NA;
  const unsigned* gbv = p.gbits + b * NA;

  float v[10];   // top-10 ious, descending (zeros = reference zero-padding)
  u64   kv[10];  // bottom-10 lex (cost, idx) as sortable keys, ascending
#pragma unroll
  for (int j = 0; j < 10; j++) { v[j] = 0.0f; kv[j] = ~0ull; }

  {
    const float* f = p.f8;
    int cbase = b * 85 * 6400 + (5 + cg) * 6400;
    for (int al = tid; al < 6400; al += SELB) SCAN_ONE(al, f[cbase + al]);
  }
  {
    const float* f = p.f16;
    int cbase = b * 85 * 1600 + (5 + cg) * 1600;
    for (int al = tid; al < 1600; al += SELB) SCAN_ONE(6400 + al, f[cbase + al]);
  }
  {
    const float* f = p.f32;
    int cbase = b * 85 * 400 + (5 + cg) * 400;
    for (int al = tid; al < 400; al += SELB) SCAN_ONE(8000 + al, f[cbase + al]);
  }

  // dyn_k = max(floor(sum top-10 ious), 1)
  float sum = 0.0f; int ptr = 0;
  for (int it = 0; it < 10; it++) {
    float mv = (ptr < 10) ? v[ptr] : -1e30f;
    int   mi = tid;
    block_argmax(mv, mi, tid, swv, swi);
    if (tid == mi) ptr++;
    sum += mv;
  }
  int dynk = (int)sum;
  if (dynk < 1) dynk = 1;

  // pop dyn_k smallest keys; each popped real key = matched anchor
  ptr = 0;
  unsigned* mrow = p.mmask + b * NA;
  unsigned gbit = 1u << g;
  for (int it = 0; it < dynk; it++) {
    u64 mk = (ptr < 10) ? kv[ptr] : ~0ull;
    u64 win = block_min_u64(mk, tid, swk);
    if (ptr < 10 && kv[ptr] == win) {   // idx embedded => unique owner
      if (win != ~0ull) atomicOr(&mrow[(unsigned)(win & 0xFFFFFFFFu)], gbit);
      ptr++;
    }
  }
}

__device__ __forceinline__ float block_sum(float val, volatile float* sw) {
#pragma unroll
  for (int off = 32; off > 0; off >>= 1) val += __shfl_down(val, off, 64);
  int lane = threadIdx.x & 63, wv = threadIdx.x >> 6;
  __syncthreads();
  if (lane == 0) sw[wv] = val;
  __syncthreads();
  float r = 0.0f;
  if (threadIdx.x == 0) r = sw[0] + sw[1] + sw[2] + sw[3];
  return r;
}

// K3: per (b,a) dedup (wave-coop cost recompute for am>1) + losses.
// NO contended atomics: per-block partial sums to a private slot.
__global__ __launch_bounds__(256) void k_match(Params p) {
  __shared__ float sred[4];
  int b = blockIdx.y;
  int tid = threadIdx.x;
  int lane = tid & 63;
  int a = blockIdx.x * 256 + tid;
  bool valid = a < NA;

  float l_iou = 0.0f, l_obj = 0.0f, l_cls = 0.0f, l_nfg = 0.0f;
  unsigned mask = 0; int am = 0;
  bool fg = false; float pred_iou = 0.0f; int cg_ = 0;

  if (valid) {
    mask = p.mmask[b * NA + a];
    am = __popc(mask);
    fg = (mask != 0u);
    float ol = p.objlog[b * NA + a];
    float tfg = fg ? 1.0f : 0.0f;
    l_obj = fmaxf(ol, 0.0f) - ol * tfg + __logf(1.0f + __expf(-fabsf(ol)));
  }

  // wave-coop dedup: lanes 0..29 recompute the cost column, lex argmin (cost,g)
  unsigned long long amb = __ballot(valid && am > 1);
  while (amb) {
    int src = __ffsll(amb) - 1;
    amb &= amb - 1ull;
    int aa = __shfl(a, src, 64);
    float4 pb = ((const float4*)p.bbox)[b * NA + aa];
    float po_ = p.po[b * NA + aa];
    float bs_ = p.base_[b * NA + aa];
    unsigned gb_ = p.gbits[b * NA + aa];

    int lvl = (aa < 6400) ? 0 : (aa < 8000) ? 1 : 2;
    int hw  = (lvl == 0) ? 6400 : (lvl == 1) ? 1600 : 400;
    int loff = (lvl == 0) ? 0 : (lvl == 1) ? 6400 : 8000;
    const float* f = (lvl == 0) ? p.f8 : (lvl == 1) ? p.f16 : p.f32;
    int cb = b * 85 * hw + 5 * hw + (aa - loff);

    float c = 3.4e38f; int gg = 0x7FFFFFFF;
    if (lane < NG) {
      const float* gtg = p.lab + (b * NG + lane) * 5;
      float gx = gtg[0], gy = gtg[1], gw = gtg[2], gh = gtg[3];
      int cg = (int)gtg[4];
      float xl = f[cb + cg * hw];
      float iou_;
      c = cost_of(pb, po_, bs_, gb_, lane,
                  gx - 0.5f * gw, gy - 0.5f * gh,
                  gx + 0.5f * gw, gy + 0.5f * gh, gw * gh, xl, iou_);
      gg = lane;
    }
#pragma unroll
    for (int off = 32; off; off >>= 1) {
      float c2 = __shfl_down(c, off, 64);
      int   g2 = __shfl_down(gg, off, 64);
      if (c2 < c || (c2 == c && g2 < gg)) { c = c2; gg = g2; }
    }
    gg = __shfl(gg, 0, 64);
    if (lane == src) mask = 1u << gg;
  }

  if (valid && fg) {
    l_nfg = 1.0f;
    int mg = __ffs(mask) - 1;
    const float* gtm = p.lab + (b * NG + mg) * 5;
    float gx = gtm[0], gy = gtm[1], gw = gtm[2], gh = gtm[3];
    cg_ = (int)gtm[4];
    float4 pb = ((const float4*)p.bbox)[b * NA + a];
    float iou = pair_iou(pb.x, pb.y, pb.z, pb.w,
                         gx - 0.5f * gw, gy - 0.5f * gh,
                         gx + 0.5f * gw, gy + 0.5f * gh, gw * gh);
    pred_iou = iou;
    l_iou = 1.0f - iou * iou;
  }

  // wave-cooperative cls-loss for fg anchors
  unsigned long long fgb = __ballot(valid && fg);
  while (fgb) {
    int src = __ffsll(fgb) - 1;
    fgb &= fgb - 1ull;
    int   aa   = __shfl(a, src, 64);
    float piou = __shfl(pred_iou, src, 64);
    int   ccg  = __shfl(cg_, src, 64);

    int lvl = (aa < 6400) ? 0 : (aa < 8000) ? 1 : 2;
    int hw  = (lvl == 0) ? 6400 : (lvl == 1) ? 1600 : 400;
    int loff = (lvl == 0) ? 0 : (lvl == 1) ? 6400 : 8000;
    const float* f = (lvl == 0) ? p.f8 : (lvl == 1) ? p.f16 : p.f32;
    int cb = b * 85 * hw + 5 * hw + (aa - loff);

    float part = 0.0f;
#pragma unroll
    for (int c0 = 0; c0 < NC; c0 += 64) {
      int c = c0 + lane;
      if (c < NC) {
        float xl = f[cb + c * hw];
        float t = (c == ccg) ? piou : 0.0f;
        part += fmaxf(xl, 0.0f) - xl * t + __logf(1.0f + __expf(-fabsf(xl)));
      }
    }
#pragma unroll
    for (int off = 32; off; off >>= 1) part += __shfl_down(part, off, 64);
    if (lane == 0) l_cls += part;
  }

  float s0 = block_sum(l_iou, sred);
  float s1 = block_sum(l_obj, sred);
  float s2 = block_sum(l_cls, sred);
  float s3 = block_sum(l_nfg, sred);
  if (tid == 0) {
    ((float4*)p.part)[b * MGRIDX + blockIdx.x] = make_float4(s0, s1, s2, s3);
  }
}

// K4: single block sums the per-block partials and writes the loss.
__global__ __launch_bounds__(256) void k_final(Params p) {
  __shared__ float sred[4];
  int tid = threadIdx.x;
  float s0 = 0.0f, s1 = 0.0f, s2 = 0.0f, s3 = 0.0f;
  for (int i = tid; i < NBLK; i += 256) {
    float4 v = ((const float4*)p.part)[i];
    s0 += v.x; s1 += v.y; s2 += v.z; s3 += v.w;
  }
  s0 = block_sum(s0, sred);
  s1 = block_sum(s1, sred);
  s2 = block_sum(s2, sred);
  s3 = block_sum(s3, sred);
  if (tid == 0) {
    p.out[0] = (5.0f * s0 + 0.1f * s1 + s2) / fmaxf(s3, 1.0f);
  }
}

extern "C" void kernel_launch(void* const* d_in, const int* in_sizes, int n_in,
                              void* d_out, int out_size, void* d_ws, size_t ws_size,
                              hipStream_t stream) {
  Params p;
  p.f8  = (const float*)d_in[0];
  p.f16 = (const float*)d_in[1];
  p.f32 = (const float*)d_in[2];
  p.lab = (const float*)d_in[3];

  float* w = (float*)d_ws;
  p.bbox   = w;              w += (size_t)NB * NA * 4;
  p.objlog = w;              w += (size_t)NB * NA;
  p.po     = w;              w += (size_t)NB * NA;
  p.base_  = w;              w += (size_t)NB * NA;
  p.gbits  = (unsigned*)w;   w += (size_t)NB * NA;
  p.mmask  = (unsigned*)w;   w += (size_t)NB * NA;
  p.part   = w;              w += (size_t)NBLK * 4;
  p.out    = (float*)d_out;

  dim3 gd(MGRIDX, NB);
  k_stage<<<gd, 256, 0, stream>>>(p);
  k_sel<<<NB * NG, SELB, 0, stream>>>(p);
  k_match<<<gd, 256, 0, stream>>>(p);
  k_final<<<1, 256, 0, stream>>>(p);
}